// Round 13
// baseline (187.091 us; speedup 1.0000x reference)
//
#include <hip/hip_runtime.h>
#include <math.h>

namespace {

constexpr int NB = 4, NS = 2048, ND = 256, NH = 4, NDK = 64, NL = 2, NT = 1000;
constexpr float L2E = 1.44269504089f;       // log2(e)
constexpr float QSCALE = 0.125f * L2E;      // 1/sqrt(DK) * log2(e), folded into Wq/bq

typedef short bfx8 __attribute__((ext_vector_type(8)));
typedef float f32x4 __attribute__((ext_vector_type(4)));

static __device__ __forceinline__ short f2bf(float f) {
  union { float f; unsigned u; } v; v.f = f;
  unsigned u = v.u;
  unsigned r = (u + 0x7fffu + ((u >> 16) & 1u)) >> 16;   // RNE
  return (short)r;
}
static __device__ __forceinline__ float bf2f(short s) {
  union { float f; unsigned u; } v; v.u = ((unsigned)(unsigned short)s) << 16;
  return v.f;
}
static __device__ __forceinline__ float exp2_hw(float x) {
  float r;
  asm("v_exp_f32 %0, %1" : "=v"(r) : "v"(x));
  return r;
}
static __device__ __forceinline__ unsigned cvt_pk_bf16(float lo, float hi) {
  unsigned d;
  asm("v_cvt_pk_bf16_f32 %0, %1, %2" : "=v"(d) : "v"(lo), "v"(hi));
  return d;
}

// ---------------- weight pack: W[K][N] fp32 -> WT[N][K] bf16 (+bias pack) ----
__global__ __launch_bounds__(256) void k_packw(const float* __restrict__ Wq,
                                               const float* __restrict__ Wk,
                                               const float* __restrict__ Wv,
                                               const float* __restrict__ Wo,
                                               const float* __restrict__ bq,
                                               const float* __restrict__ bk,
                                               const float* __restrict__ bv,
                                               short* __restrict__ wqkvT,
                                               short* __restrict__ woT,
                                               float* __restrict__ bqkv) {
  __shared__ float t[64][65];
  int z = blockIdx.z, l = z >> 2, mat = z & 3;
  const float* src;
  short* dst;
  float scale = 1.f;
  if (mat == 0)      { src = Wq + (size_t)l * 65536; dst = wqkvT + (size_t)l * 768 * 256; scale = QSCALE; }
  else if (mat == 1) { src = Wk + (size_t)l * 65536; dst = wqkvT + (size_t)l * 768 * 256 + 256 * 256; }
  else if (mat == 2) { src = Wv + (size_t)l * 65536; dst = wqkvT + (size_t)l * 768 * 256 + 512 * 256; }
  else               { src = Wo + (size_t)l * 65536; dst = woT + (size_t)l * 65536; }
  int k0 = blockIdx.x * 64, n0 = blockIdx.y * 64;
  int c = threadIdx.x & 63, r4 = threadIdx.x >> 6;
  #pragma unroll
  for (int rr = 0; rr < 64; rr += 4) t[rr + r4][c] = src[(size_t)(k0 + rr + r4) * 256 + n0 + c];
  __syncthreads();
  #pragma unroll
  for (int rr = 0; rr < 64; rr += 4) {
    int n = rr + r4;
    dst[(size_t)(n0 + n) * 256 + k0 + c] = f2bf(t[c][n] * scale);
  }
  if (mat == 0 && blockIdx.x == 0 && blockIdx.y == 0) {
    for (int cc = threadIdx.x; cc < 768; cc += 256) {
      float v = cc < 256 ? bq[l * 256 + cc] * QSCALE
                         : (cc < 512 ? bk[l * 256 + cc - 256] : bv[l * 256 + cc - 512]);
      bqkv[l * 768 + cc] = v;
    }
  }
}

// ---------------- embedding gather (float4, 4 rows/block) --------------------
__global__ __launch_bounds__(256) void k_embed(const int* __restrict__ x,
                                               const int* __restrict__ td,
                                               const float* __restrict__ ee,
                                               const float* __restrict__ te,
                                               float* __restrict__ h,
                                               short* __restrict__ hb) {
  int lane = threadIdx.x & 63, r4 = threadIdx.x >> 6;
  int row = blockIdx.x * 4 + r4;
  int xi = x[row];
  int tb = td[row];
  tb = tb < 0 ? 0 : (tb >= NT ? NT - 1 : tb);
  float4 e = ((const float4*)&ee[(size_t)xi * ND])[lane];
  float4 tv = ((const float4*)&te[(size_t)tb * ND])[lane];
  float4 v;
  v.x = e.x + tv.x; v.y = e.y + tv.y; v.z = e.z + tv.z; v.w = e.w + tv.w;
  ((float4*)&h[(size_t)row * ND])[lane] = v;
  short4 ob; ob.x = f2bf(v.x); ob.y = f2bf(v.y); ob.z = f2bf(v.z); ob.w = f2bf(v.w);
  ((short4*)&hb[(size_t)row * ND])[lane] = ob;
}

// ---------------- MFMA GEMM: 64x128 tile, BK=64, K=256 -----------------------
template <int OUT_BF16>
__global__ __launch_bounds__(256) void k_gemm(const short* __restrict__ A,
                                              const short* __restrict__ BT,
                                              const float* __restrict__ bias,
                                              void* __restrict__ C, int ldc,
                                              int mb_mul, int mb_add, int n_base) {
  constexpr int LP = 76;
  __shared__ short at[64][LP];
  __shared__ short bt[128][LP];
  int tid = threadIdx.x;
  int w = tid >> 6, lane = tid & 63, ln15 = lane & 15, g = lane >> 4;
  int m0 = (blockIdx.x * mb_mul + mb_add) * 64;
  int n0 = n_base + blockIdx.y * 128;
  int srow = tid >> 2, scol = (tid & 3) * 16;      // A staging: 64 rows x 64
  int brow = tid >> 1, bcol = (tid & 1) * 32;      // B staging: 128 rows x 64

  f32x4 acc[8];
  #pragma unroll
  for (int nt = 0; nt < 8; ++nt) acc[nt] = (f32x4){0.f, 0.f, 0.f, 0.f};

  bfx8 a0, a1, b0, b1, b2, b3;
  auto LOAD = [&](int kk0) {
    const short* as = &A[(size_t)(m0 + srow) * 256 + kk0 + scol];
    a0 = *(const bfx8*)as; a1 = *(const bfx8*)(as + 8);
    const short* bs = &BT[(size_t)(n0 + brow) * 256 + kk0 + bcol];
    b0 = *(const bfx8*)bs; b1 = *(const bfx8*)(bs + 8);
    b2 = *(const bfx8*)(bs + 16); b3 = *(const bfx8*)(bs + 24);
  };
  LOAD(0);
  for (int kk0 = 0; kk0 < 256; kk0 += 64) {
    __syncthreads();
    *(bfx8*)&at[srow][scol] = a0; *(bfx8*)&at[srow][scol + 8] = a1;
    *(bfx8*)&bt[brow][bcol] = b0; *(bfx8*)&bt[brow][bcol + 8] = b1;
    *(bfx8*)&bt[brow][bcol + 16] = b2; *(bfx8*)&bt[brow][bcol + 24] = b3;
    __syncthreads();
    if (kk0 + 64 < 256) LOAD(kk0 + 64);
    #pragma unroll
    for (int ks = 0; ks < 2; ++ks) {
      bfx8 af = *(const bfx8*)&at[w * 16 + ln15][ks * 32 + g * 8];
      #pragma unroll
      for (int nt = 0; nt < 8; ++nt) {
        bfx8 bf = *(const bfx8*)&bt[nt * 16 + ln15][ks * 32 + g * 8];
        acc[nt] = __builtin_amdgcn_mfma_f32_16x16x32_bf16(af, bf, acc[nt], 0, 0, 0);
      }
    }
  }

  #pragma unroll
  for (int nt = 0; nt < 8; ++nt) {
    int col = n0 + nt * 16 + ln15;
    float bb = bias[col];
    #pragma unroll
    for (int r = 0; r < 4; ++r) {
      int row = m0 + w * 16 + g * 4 + r;
      float val = acc[nt][r] + bb;
      if (OUT_BF16) ((short*)C)[(size_t)row * ldc + col] = f2bf(val);
      else          ((float*)C)[(size_t)row * ldc + col] = val;
    }
  }
}

// ---------------- V^T + bias prepass (per layer) -----------------------------
__global__ __launch_bounds__(256) void k_frag(const short* __restrict__ qkv,
                                              const int* __restrict__ td,
                                              const int* __restrict__ mask,
                                              const float* __restrict__ tp,
                                              short* __restrict__ vT,
                                              float* __restrict__ sbias_g) {
  __shared__ short vl[64][72];
  int tile = blockIdx.x, hh = blockIdx.y, b = blockIdx.z;
  int t = threadIdx.x;
  int k0 = tile * 64;
  {
    int key = t >> 2, dg = (t & 3) * 16;
    const short* vsrc = &qkv[(size_t)(b * NS + k0 + key) * 768 + 512 + hh * NDK + dg];
    bfx8 v0 = *(const bfx8*)vsrc, v1 = *(const bfx8*)(vsrc + 8);
    *(bfx8*)&vl[key][dg] = v0;
    *(bfx8*)&vl[key][dg + 8] = v1;
  }
  if (t < 64) {
    int kk = k0 + t;
    int tb = td[b * NS + kk];
    tb = tb < 0 ? 0 : (tb >= NT ? NT - 1 : tb);
    sbias_g[(size_t)(b * NH + hh) * NS + kk] = mask[b * NS + kk] ? tp[tb * NH + hh] * L2E : -1e9f;
  }
  __syncthreads();
  int dim = t >> 2, c0 = (t & 3) * 16;
  short outv[16];
  #pragma unroll
  for (int j = 0; j < 16; ++j) {
    int c = c0 + j;
    // inverse of vcol(key): key = (c>>5)*32 + ((c>>2)&1)*16 + ((c>>3)&3)*4 + (c&3)
    int kk = ((c >> 5) << 5) | (((c >> 2) & 1) << 4) | (((c >> 3) & 3) << 2) | (c & 3);
    outv[j] = vl[kk][dim];
  }
  short* dst = &vT[(((size_t)(b * NH + hh) * 32 + tile) * 64 + dim) * 64 + c0];
  *(int4*)dst = *(const int4*)outv;
  *(int4*)(dst + 8) = *(const int4*)(outv + 8);
}

// ---------------- MFMA flash attention: 32 queries/wave ----------------------
// 512 threads = 8 waves = 4 wsub(32q) x 2 half(keys). Block: 128q x 128keys
// per iter. Each kf/vf LDS fragment read feeds TWO MFMAs (query groups qs=0,1)
// -> LDS reads per unit work halved vs 16q/wave (the R12 bottleneck).
// launch_bounds (512,2): 128-VGPR cap under min-blocks semantics (R10-12 evidence).
__global__ __launch_bounds__(512, 2) void k_attn(const short* __restrict__ qkv,
                                                 const short* __restrict__ vT,
                                                 const float* __restrict__ sbias_g,
                                                 short* __restrict__ ctx,
                                                 short* __restrict__ partO,
                                                 float* __restrict__ partML,
                                                 int q_base, int qcount, int nchunk) {
  constexpr int LP = 76;
  __shared__ short smem[2 * 2 * 64 * LP];  // kt[2][64][76] | vt[2][64][76] = 38912 B
  __shared__ float sbias[2][64];
  __shared__ float shML[256];              // [128 q][m, l]
  short (*kt)[64][LP] = (short(*)[64][LP])smem;
  short (*vt)[64][LP] = (short(*)[64][LP])(smem + 2 * 64 * LP);

  int tid = threadIdx.x;
  int w = tid >> 6, lane = tid & 63, ln15 = lane & 15, g = lane >> 4;
  int half = w >> 2, wsub = w & 3;
  int t = tid & 255;
  int b = blockIdx.z, hh = blockIdx.y;
  int qtile = blockIdx.x / nchunk;
  int chunk = blockIdx.x - qtile * nchunk;
  int niter = NS / (128 * nchunk);
  int tbase = chunk * (NS / 64 / nchunk);
  int q0 = q_base + qtile * 128;
  int qw0 = q0 + wsub * 32;

  // Q fragments for two 16-query column groups
  bfx8 aq0[2], aq1[2];
  #pragma unroll
  for (int ks = 0; ks < 2; ++ks) {
    aq0[ks] = *(const bfx8*)&qkv[(size_t)(b * NS + qw0 + ln15) * 768 + hh * NDK + ks * 32 + g * 8];
    aq1[ks] = *(const bfx8*)&qkv[(size_t)(b * NS + qw0 + 16 + ln15) * 768 + hh * NDK + ks * 32 + g * 8];
  }

  f32x4 o0[4], o1[4];
  #pragma unroll
  for (int dt = 0; dt < 4; ++dt) { o0[dt] = (f32x4){0.f,0.f,0.f,0.f}; o1[dt] = (f32x4){0.f,0.f,0.f,0.f}; }
  float m0v = -1e30f, m1v = -1e30f, ls0 = 0.f, ls1 = 0.f;

  int srow = t >> 2, scg = (t & 3) * 16;

  bfx8 kr0, kr1, vr0, vr1;
  float br = 0.f;
  auto loadset = [&](int it) {
    int tt = tbase + half * niter + it;
    int k0 = tt * 64;
    const short* ksrc = &qkv[(size_t)(b * NS + k0 + srow) * 768 + 256 + hh * NDK + scg];
    kr0 = *(const bfx8*)ksrc; kr1 = *(const bfx8*)(ksrc + 8);
    const short* vsrc = &vT[(((size_t)(b * NH + hh) * 32 + tt) * 64 + srow) * 64 + scg];
    vr0 = *(const bfx8*)vsrc; vr1 = *(const bfx8*)(vsrc + 8);
    if (t < 64) br = sbias_g[(size_t)(b * NH + hh) * NS + k0 + t];
  };

  auto compute = [&]() {
    f32x4 c0[4], c1[4];
    __builtin_amdgcn_s_setprio(1);
    #pragma unroll
    for (int nt = 0; nt < 4; ++nt) {
      c0[nt] = (f32x4){0.f,0.f,0.f,0.f};
      c1[nt] = (f32x4){0.f,0.f,0.f,0.f};
      #pragma unroll
      for (int ks = 0; ks < 2; ++ks) {
        bfx8 kf = *(const bfx8*)&kt[half][nt * 16 + ln15][ks * 32 + g * 8];
        c0[nt] = __builtin_amdgcn_mfma_f32_16x16x32_bf16(kf, aq0[ks], c0[nt], 0, 0, 0);
        c1[nt] = __builtin_amdgcn_mfma_f32_16x16x32_bf16(kf, aq1[ks], c1[nt], 0, 0, 0);
      }
    }
    __builtin_amdgcn_s_setprio(0);
    #pragma unroll
    for (int nt = 0; nt < 4; ++nt) {
      float4 bb = *(const float4*)&sbias[half][nt * 16 + g * 4];
      c0[nt][0] += bb.x; c0[nt][1] += bb.y; c0[nt][2] += bb.z; c0[nt][3] += bb.w;
      c1[nt][0] += bb.x; c1[nt][1] += bb.y; c1[nt][2] += bb.z; c1[nt][3] += bb.w;
    }
    float rm0 = c0[0][0], rm1 = c1[0][0];
    #pragma unroll
    for (int nt = 0; nt < 4; ++nt)
      #pragma unroll
      for (int r = 0; r < 4; ++r) { rm0 = fmaxf(rm0, c0[nt][r]); rm1 = fmaxf(rm1, c1[nt][r]); }
    rm0 = fmaxf(rm0, __shfl_xor(rm0, 16, 64)); rm0 = fmaxf(rm0, __shfl_xor(rm0, 32, 64));
    rm1 = fmaxf(rm1, __shfl_xor(rm1, 16, 64)); rm1 = fmaxf(rm1, __shfl_xor(rm1, 32, 64));
    if (__any((rm0 > m0v + 10.f) || (rm1 > m1v + 10.f))) {
      float nm0 = fmaxf(m0v, rm0), nm1 = fmaxf(m1v, rm1);
      float s0 = exp2_hw(m0v - nm0), s1 = exp2_hw(m1v - nm1);
      m0v = nm0; m1v = nm1; ls0 *= s0; ls1 *= s1;
      #pragma unroll
      for (int dt = 0; dt < 4; ++dt)
        #pragma unroll
        for (int r = 0; r < 4; ++r) { o0[dt][r] *= s0; o1[dt][r] *= s1; }
    }
    unsigned pb0[2][4], pb1[2][4];
    float ts0 = 0.f, ts1 = 0.f;
    #pragma unroll
    for (int nt = 0; nt < 4; ++nt) {
      float a0 = exp2_hw(c0[nt][0] - m0v), a1 = exp2_hw(c0[nt][1] - m0v);
      float a2 = exp2_hw(c0[nt][2] - m0v), a3 = exp2_hw(c0[nt][3] - m0v);
      ts0 += (a0 + a1) + (a2 + a3);
      pb0[nt >> 1][(nt & 1) * 2]     = cvt_pk_bf16(a0, a1);
      pb0[nt >> 1][(nt & 1) * 2 + 1] = cvt_pk_bf16(a2, a3);
      float e0 = exp2_hw(c1[nt][0] - m1v), e1 = exp2_hw(c1[nt][1] - m1v);
      float e2 = exp2_hw(c1[nt][2] - m1v), e3 = exp2_hw(c1[nt][3] - m1v);
      ts1 += (e0 + e1) + (e2 + e3);
      pb1[nt >> 1][(nt & 1) * 2]     = cvt_pk_bf16(e0, e1);
      pb1[nt >> 1][(nt & 1) * 2 + 1] = cvt_pk_bf16(e2, e3);
    }
    ls0 += ts0; ls1 += ts1;
    __builtin_amdgcn_s_setprio(1);
    #pragma unroll
    for (int ks = 0; ks < 2; ++ks) {
      union { unsigned u[4]; bfx8 v; } pf0, pf1;
      pf0.u[0] = pb0[ks][0]; pf0.u[1] = pb0[ks][1]; pf0.u[2] = pb0[ks][2]; pf0.u[3] = pb0[ks][3];
      pf1.u[0] = pb1[ks][0]; pf1.u[1] = pb1[ks][1]; pf1.u[2] = pb1[ks][2]; pf1.u[3] = pb1[ks][3];
      #pragma unroll
      for (int dt = 0; dt < 4; ++dt) {
        bfx8 vf = *(const bfx8*)&vt[half][dt * 16 + ln15][ks * 32 + g * 8];
        o0[dt] = __builtin_amdgcn_mfma_f32_16x16x32_bf16(vf, pf0.v, o0[dt], 0, 0, 0);
        o1[dt] = __builtin_amdgcn_mfma_f32_16x16x32_bf16(vf, pf1.v, o1[dt], 0, 0, 0);
      }
    }
    __builtin_amdgcn_s_setprio(0);
  };

  loadset(0);
  for (int it = 0; it < niter; ++it) {
    __syncthreads();
    *(bfx8*)&kt[half][srow][scg] = kr0;
    *(bfx8*)&kt[half][srow][scg + 8] = kr1;
    *(bfx8*)&vt[half][srow][scg] = vr0;
    *(bfx8*)&vt[half][srow][scg + 8] = vr1;
    if (t < 64) sbias[half][t] = br;
    __syncthreads();
    if (it + 1 < niter) loadset(it + 1);
    compute();
  }

  ls0 += __shfl_xor(ls0, 16, 64); ls0 += __shfl_xor(ls0, 32, 64);
  ls1 += __shfl_xor(ls1, 16, 64); ls1 += __shfl_xor(ls1, 32, 64);

  // ---- merge halves (each lane owns queries qA=wsub*32+ln15, qB=qA+16) ----
  float* shO = (float*)smem;   // [128 q][68 stride] fp32 = 34816 B <= 38912
  __syncthreads();
  int qA = wsub * 32 + ln15, qB = qA + 16;
  if (half == 1) {
    #pragma unroll
    for (int dt = 0; dt < 4; ++dt) {
      float4 s0; s0.x = o0[dt][0]; s0.y = o0[dt][1]; s0.z = o0[dt][2]; s0.w = o0[dt][3];
      *(float4*)&shO[qA * 68 + dt * 16 + g * 4] = s0;
      float4 s1; s1.x = o1[dt][0]; s1.y = o1[dt][1]; s1.z = o1[dt][2]; s1.w = o1[dt][3];
      *(float4*)&shO[qB * 68 + dt * 16 + g * 4] = s1;
    }
    if (g == 0) {
      shML[qA * 2] = m0v; shML[qA * 2 + 1] = ls0;
      shML[qB * 2] = m1v; shML[qB * 2 + 1] = ls1;
    }
  }
  __syncthreads();
  if (half == 0) {
    #pragma unroll
    for (int qs = 0; qs < 2; ++qs) {
      int q = qs ? qB : qA;
      float mm = qs ? m1v : m0v;
      float ll = qs ? ls1 : ls0;
      const f32x4* oo = qs ? o1 : o0;
      float m2 = shML[q * 2], l2 = shML[q * 2 + 1];
      float M = fmaxf(mm, m2);
      float fa = exp2_hw(mm - M), fb = exp2_hw(m2 - M);
      if (nchunk == 1) {
        float inv = 1.f / (ll * fa + l2 * fb);
        fa *= inv; fb *= inv;
        #pragma unroll
        for (int dt = 0; dt < 4; ++dt) {
          float4 sh = *(const float4*)&shO[q * 68 + dt * 16 + g * 4];
          float v0 = oo[dt][0] * fa + sh.x * fb;
          float v1 = oo[dt][1] * fa + sh.y * fb;
          float v2 = oo[dt][2] * fa + sh.z * fb;
          float v3 = oo[dt][3] * fa + sh.w * fb;
          int2 pk; pk.x = (int)cvt_pk_bf16(v0, v1); pk.y = (int)cvt_pk_bf16(v2, v3);
          *(int2*)&ctx[(size_t)(b * NS + q0 + q) * ND + hh * NDK + dt * 16 + g * 4] = pk;
        }
      } else {
        float L = ll * fa + l2 * fb;
        size_t rowi = (size_t)(chunk * 16 + b * NH + hh) * qcount + qtile * 128 + q;
        #pragma unroll
        for (int dt = 0; dt < 4; ++dt) {
          float4 sh = *(const float4*)&shO[q * 68 + dt * 16 + g * 4];
          float v0 = oo[dt][0] * fa + sh.x * fb;
          float v1 = oo[dt][1] * fa + sh.y * fb;
          float v2 = oo[dt][2] * fa + sh.z * fb;
          float v3 = oo[dt][3] * fa + sh.w * fb;
          int2 pk; pk.x = (int)cvt_pk_bf16(v0, v1); pk.y = (int)cvt_pk_bf16(v2, v3);
          *(int2*)&partO[rowi * 64 + dt * 16 + g * 4] = pk;
        }
        if (g == 0) { partML[rowi * 2] = M; partML[rowi * 2 + 1] = L; }
      }
    }
  }
}

// ---------------- flash-decode merge: combine nchunk bf16 partials -----------
__global__ __launch_bounds__(256) void k_amerge(const short* __restrict__ partO,
                                                const float* __restrict__ partML,
                                                short* __restrict__ ctx,
                                                int q_base, int qcount, int nchunk) {
  int b = blockIdx.z, hh = blockIdx.y;
  int qi = blockIdx.x * 64 + (threadIdx.x >> 2);
  int d0 = (threadIdx.x & 3) * 16;
  int bh = b * NH + hh;
  float M = -1e30f;
  for (int c = 0; c < nchunk; ++c)
    M = fmaxf(M, partML[((size_t)(c * 16 + bh) * qcount + qi) * 2]);
  float L = 0.f;
  float acc[16];
  #pragma unroll
  for (int i = 0; i < 16; ++i) acc[i] = 0.f;
  for (int c = 0; c < nchunk; ++c) {
    size_t row = (size_t)(c * 16 + bh) * qcount + qi;
    float mc = partML[row * 2];
    float lc = partML[row * 2 + 1];
    float s = exp2_hw(mc - M);
    L += lc * s;
    union { int4 v; short sh[8]; } u0, u1;
    u0.v = *(const int4*)&partO[row * 64 + d0];
    u1.v = *(const int4*)&partO[row * 64 + d0 + 8];
    #pragma unroll
    for (int i = 0; i < 8; ++i) {
      acc[i]     += bf2f(u0.sh[i]) * s;
      acc[8 + i] += bf2f(u1.sh[i]) * s;
    }
  }
  float inv = 1.f / L;
  short res[16];
  #pragma unroll
  for (int i = 0; i < 16; ++i) res[i] = f2bf(acc[i] * inv);
  short* dst = &ctx[(size_t)(b * NS + q_base + qi) * ND + hh * NDK + d0];
  *(int4*)dst = *(const int4*)res;
  *(int4*)(dst + 8) = *(const int4*)(res + 8);
}

// ---------------- layernorm: 4 rows/block, shuffle-reduce --------------------
__global__ __launch_bounds__(256) void k_ln(float* __restrict__ h,
                                            short* __restrict__ hb,
                                            const float* __restrict__ g_,
                                            const float* __restrict__ b_, int q_base) {
  int lane = threadIdx.x & 63, r4 = threadIdx.x >> 6;
  size_t row = (size_t)blockIdx.y * NS + q_base + blockIdx.x * 4 + r4;
  float4 v = ((const float4*)&h[row * ND])[lane];
  float s = v.x + v.y + v.z + v.w;
  #pragma unroll
  for (int off = 1; off < 64; off <<= 1) s += __shfl_xor(s, off, 64);
  float mu = s * (1.f / ND);
  float dx = v.x - mu, dy = v.y - mu, dz = v.z - mu, dw = v.w - mu;
  float q = dx * dx + dy * dy + dz * dz + dw * dw;
  #pragma unroll
  for (int off = 1; off < 64; off <<= 1) q += __shfl_xor(q, off, 64);
  float rr = rsqrtf(q * (1.f / ND) + 1e-5f);
  float4 gg = ((const float4*)g_)[lane];
  float4 bb = ((const float4*)b_)[lane];
  float4 o;
  o.x = dx * rr * gg.x + bb.x;
  o.y = dy * rr * gg.y + bb.y;
  o.z = dz * rr * gg.z + bb.z;
  o.w = dw * rr * gg.w + bb.w;
  ((float4*)&h[row * ND])[lane] = o;
  short4 ob; ob.x = f2bf(o.x); ob.y = f2bf(o.y); ob.z = f2bf(o.z); ob.w = f2bf(o.w);
  ((short4*)&hb[row * ND])[lane] = ob;
}

// ---------------- classifier head on last token ------------------------------
__global__ __launch_bounds__(128) void k_head(const float* __restrict__ h,
                                              const float* __restrict__ Wc1,
                                              const float* __restrict__ bc1,
                                              const float* __restrict__ Wc2,
                                              const float* __restrict__ bc2,
                                              float* __restrict__ out) {
  __shared__ float red[128];
  int j = threadIdx.x;
  int b = blockIdx.x;
  const float* last = &h[(size_t)(b * NS + NS - 1) * ND];
  float acc = bc1[j];
  for (int d = 0; d < ND; ++d) acc = fmaf(last[d], Wc1[d * 128 + j], acc);
  acc = fmaxf(acc, 0.f);
  red[j] = acc * Wc2[j];
  __syncthreads();
  for (int off = 64; off > 0; off >>= 1) {
    if (j < off) red[j] += red[j + off];
    __syncthreads();
  }
  if (j == 0) out[b] = 1.f / (1.f + __expf(-(red[0] + bc2[0])));
}

}  // namespace

extern "C" void kernel_launch(void* const* d_in, const int* in_sizes, int n_in,
                              void* d_out, int out_size, void* d_ws, size_t ws_size,
                              hipStream_t stream) {
  const int* x = (const int*)d_in[0];
  const int* td = (const int*)d_in[1];
  const int* mask = (const int*)d_in[2];
  const float* ee = (const float*)d_in[3];
  const float* te = (const float*)d_in[4];
  const float* Wq = (const float*)d_in[5];
  const float* bq = (const float*)d_in[6];
  const float* Wk = (const float*)d_in[7];
  const float* bk = (const float*)d_in[8];
  const float* Wv = (const float*)d_in[9];
  const float* bv = (const float*)d_in[10];
  const float* tp = (const float*)d_in[11];
  const float* Wo = (const float*)d_in[12];
  const float* bo = (const float*)d_in[13];
  const float* lng = (const float*)d_in[14];
  const float* lnb = (const float*)d_in[15];
  const float* Wc1 = (const float*)d_in[16];
  const float* bc1 = (const float*)d_in[17];
  const float* Wc2 = (const float*)d_in[18];
  const float* bc2 = (const float*)d_in[19];
  float* out = (float*)d_out;

  char* ws = (char*)d_ws;
  const size_t M = (size_t)NB * NS;  // 8192
  float* h       = (float*)(ws);                       // 8 MB
  short* hb      = (short*)(ws + (8 << 20));           // 4 MB
  short* qkv     = (short*)(ws + (12 << 20));          // 12 MB  [M][768]
  short* ctx     = (short*)(ws + (24 << 20));          // 4 MB   [M][256]
  short* wqkvT   = (short*)(ws + (28 << 20));          // 768 KB
  short* woT     = (short*)(ws + (28 << 20) + 786432); // 256 KB
  float* bqkv    = (float*)(ws + (29 << 20) + 262144); // 6 KB
  short* vT      = (short*)(ws + (30 << 20));          // 4 MB   [16 bh][32 tile][64][64]
  float* sbias_g = (float*)(ws + (34 << 20));          // 128 KB [16 bh][2048]
  // partials overlay h+hb (dead during attention; rewritten after k_amerge)
  short* partO   = (short*)(ws);                       // <=8.4 MB bf16
  float* partML  = (float*)(ws + (10 << 20));          // <=512 KB fp32

  k_packw<<<dim3(4, 4, 8), 256, 0, stream>>>(Wq, Wk, Wv, Wo, bq, bk, bv, wqkvT, woT, bqkv);
  k_embed<<<NB * NS / 4, 256, 0, stream>>>(x, td, ee, te, h, hb);

  for (int l = 0; l < NL; ++l) {
    const short* wqkvTl = wqkvT + (size_t)l * 768 * 256;
    const short* woTl = woT + (size_t)l * 65536;
    const float* bqkvl = bqkv + (size_t)l * 768;
    const float* bol = bo + (size_t)l * ND;
    const float* tpl = tp + (size_t)l * NT * NH;
    const float* lngl = lng + (size_t)l * ND;
    const float* lnbl = lnb + (size_t)l * ND;
    const bool last = (l == NL - 1);

    if (!last) {
      k_gemm<1><<<dim3(M / 64, 6), 256, 0, stream>>>(hb, wqkvTl, bqkvl, qkv, 768, 1, 0, 0);
    } else {
      k_gemm<1><<<dim3(M / 64, 4), 256, 0, stream>>>(hb, wqkvTl, bqkvl, qkv, 768, 1, 0, 256);
      k_gemm<1><<<dim3(NB, 2), 256, 0, stream>>>(hb, wqkvTl, bqkvl, qkv, 768, 32, 31, 0);
    }

    k_frag<<<dim3(32, NH, NB), 256, 0, stream>>>(qkv, td, mask, tpl, vT, sbias_g);

    if (!last) {
      // 128-q tiles, split-2 over keys: 512 blocks = 2 resident/CU, 1 round
      k_attn<<<dim3((NS / 128) * 2, NH, NB), 512, 0, stream>>>(qkv, vT, sbias_g, ctx,
                                                               partO, partML, 0, NS, 2);
      k_amerge<<<dim3(NS / 64, NH, NB), 256, 0, stream>>>(partO, partML, ctx, 0, NS, 2);
      k_gemm<0><<<dim3(M / 64, 2), 256, 0, stream>>>(ctx, woTl, bol, h, 256, 1, 0, 0);
      k_ln<<<dim3(NS / 4, NB), 256, 0, stream>>>(h, hb, lngl, lnbl, 0);
    } else {
      // last 128 q (rows NS-128..NS-65 use stale-but-finite Q; their ctx is
      // never read downstream — proj/ln/head touch only the last 64/4/1 rows)
      k_attn<<<dim3(16, NH, NB), 512, 0, stream>>>(qkv, vT, sbias_g, ctx,
                                                   partO, partML, NS - 128, 128, 16);
      k_amerge<<<dim3(2, NH, NB), 256, 0, stream>>>(partO, partML, ctx, NS - 128, 128, 16);
      k_gemm<0><<<dim3(NB, 2), 256, 0, stream>>>(ctx, woTl, bol, h, 256, 32, 31, 0);
      k_ln<<<dim3(1, NB), 256, 0, stream>>>(h, hb, lngl, lnbl, NS - 4);
    }
  }

  k_head<<<NB, 128, 0, stream>>>(h, Wc1, bc1, Wc2, bc2, out);
}

// Round 14
// 126.074 us; speedup vs baseline: 1.4840x; 1.4840x over previous
//
#include <hip/hip_runtime.h>
#include <math.h>

namespace {

constexpr int NB = 4, NS = 2048, ND = 256, NH = 4, NDK = 64, NL = 2, NT = 1000;
constexpr float L2E = 1.44269504089f;       // log2(e)
constexpr float QSCALE = 0.125f * L2E;      // 1/sqrt(DK) * log2(e), folded into Wq/bq

typedef short bfx8 __attribute__((ext_vector_type(8)));
typedef float f32x4 __attribute__((ext_vector_type(4)));

static __device__ __forceinline__ short f2bf(float f) {
  union { float f; unsigned u; } v; v.f = f;
  unsigned u = v.u;
  unsigned r = (u + 0x7fffu + ((u >> 16) & 1u)) >> 16;   // RNE
  return (short)r;
}
static __device__ __forceinline__ float bf2f(short s) {
  union { float f; unsigned u; } v; v.u = ((unsigned)(unsigned short)s) << 16;
  return v.f;
}
static __device__ __forceinline__ float exp2_hw(float x) {
  float r;
  asm("v_exp_f32 %0, %1" : "=v"(r) : "v"(x));
  return r;
}
static __device__ __forceinline__ unsigned cvt_pk_bf16(float lo, float hi) {
  unsigned d;
  asm("v_cvt_pk_bf16_f32 %0, %1, %2" : "=v"(d) : "v"(lo), "v"(hi));
  return d;
}

// ---------------- weight pack: W[K][N] fp32 -> WT[N][K] bf16 (+bias pack) ----
__global__ __launch_bounds__(256) void k_packw(const float* __restrict__ Wq,
                                               const float* __restrict__ Wk,
                                               const float* __restrict__ Wv,
                                               const float* __restrict__ Wo,
                                               const float* __restrict__ bq,
                                               const float* __restrict__ bk,
                                               const float* __restrict__ bv,
                                               short* __restrict__ wqkvT,
                                               short* __restrict__ woT,
                                               float* __restrict__ bqkv) {
  __shared__ float t[64][65];
  int z = blockIdx.z, l = z >> 2, mat = z & 3;
  const float* src;
  short* dst;
  float scale = 1.f;
  if (mat == 0)      { src = Wq + (size_t)l * 65536; dst = wqkvT + (size_t)l * 768 * 256; scale = QSCALE; }
  else if (mat == 1) { src = Wk + (size_t)l * 65536; dst = wqkvT + (size_t)l * 768 * 256 + 256 * 256; }
  else if (mat == 2) { src = Wv + (size_t)l * 65536; dst = wqkvT + (size_t)l * 768 * 256 + 512 * 256; }
  else               { src = Wo + (size_t)l * 65536; dst = woT + (size_t)l * 65536; }
  int k0 = blockIdx.x * 64, n0 = blockIdx.y * 64;
  int c = threadIdx.x & 63, r4 = threadIdx.x >> 6;
  #pragma unroll
  for (int rr = 0; rr < 64; rr += 4) t[rr + r4][c] = src[(size_t)(k0 + rr + r4) * 256 + n0 + c];
  __syncthreads();
  #pragma unroll
  for (int rr = 0; rr < 64; rr += 4) {
    int n = rr + r4;
    dst[(size_t)(n0 + n) * 256 + k0 + c] = f2bf(t[c][n] * scale);
  }
  if (mat == 0 && blockIdx.x == 0 && blockIdx.y == 0) {
    for (int cc = threadIdx.x; cc < 768; cc += 256) {
      float v = cc < 256 ? bq[l * 256 + cc] * QSCALE
                         : (cc < 512 ? bk[l * 256 + cc - 256] : bv[l * 256 + cc - 512]);
      bqkv[l * 768 + cc] = v;
    }
  }
}

// ---------------- embedding gather (float4, 4 rows/block) --------------------
__global__ __launch_bounds__(256) void k_embed(const int* __restrict__ x,
                                               const int* __restrict__ td,
                                               const float* __restrict__ ee,
                                               const float* __restrict__ te,
                                               float* __restrict__ h,
                                               short* __restrict__ hb) {
  int lane = threadIdx.x & 63, r4 = threadIdx.x >> 6;
  int row = blockIdx.x * 4 + r4;
  int xi = x[row];
  int tb = td[row];
  tb = tb < 0 ? 0 : (tb >= NT ? NT - 1 : tb);
  float4 e = ((const float4*)&ee[(size_t)xi * ND])[lane];
  float4 tv = ((const float4*)&te[(size_t)tb * ND])[lane];
  float4 v;
  v.x = e.x + tv.x; v.y = e.y + tv.y; v.z = e.z + tv.z; v.w = e.w + tv.w;
  ((float4*)&h[(size_t)row * ND])[lane] = v;
  short4 ob; ob.x = f2bf(v.x); ob.y = f2bf(v.y); ob.z = f2bf(v.z); ob.w = f2bf(v.w);
  ((short4*)&hb[(size_t)row * ND])[lane] = ob;
}

// ---------------- MFMA GEMM: 64x128 tile, BK=64, K=256 -----------------------
template <int OUT_BF16>
__global__ __launch_bounds__(256) void k_gemm(const short* __restrict__ A,
                                              const short* __restrict__ BT,
                                              const float* __restrict__ bias,
                                              void* __restrict__ C, int ldc,
                                              int mb_mul, int mb_add, int n_base) {
  constexpr int LP = 76;
  __shared__ short at[64][LP];
  __shared__ short bt[128][LP];
  int tid = threadIdx.x;
  int w = tid >> 6, lane = tid & 63, ln15 = lane & 15, g = lane >> 4;
  int m0 = (blockIdx.x * mb_mul + mb_add) * 64;
  int n0 = n_base + blockIdx.y * 128;
  int srow = tid >> 2, scol = (tid & 3) * 16;      // A staging: 64 rows x 64
  int brow = tid >> 1, bcol = (tid & 1) * 32;      // B staging: 128 rows x 64

  f32x4 acc[8];
  #pragma unroll
  for (int nt = 0; nt < 8; ++nt) acc[nt] = (f32x4){0.f, 0.f, 0.f, 0.f};

  bfx8 a0, a1, b0, b1, b2, b3;
  auto LOAD = [&](int kk0) {
    const short* as = &A[(size_t)(m0 + srow) * 256 + kk0 + scol];
    a0 = *(const bfx8*)as; a1 = *(const bfx8*)(as + 8);
    const short* bs = &BT[(size_t)(n0 + brow) * 256 + kk0 + bcol];
    b0 = *(const bfx8*)bs; b1 = *(const bfx8*)(bs + 8);
    b2 = *(const bfx8*)(bs + 16); b3 = *(const bfx8*)(bs + 24);
  };
  LOAD(0);
  for (int kk0 = 0; kk0 < 256; kk0 += 64) {
    __syncthreads();
    *(bfx8*)&at[srow][scol] = a0; *(bfx8*)&at[srow][scol + 8] = a1;
    *(bfx8*)&bt[brow][bcol] = b0; *(bfx8*)&bt[brow][bcol + 8] = b1;
    *(bfx8*)&bt[brow][bcol + 16] = b2; *(bfx8*)&bt[brow][bcol + 24] = b3;
    __syncthreads();
    if (kk0 + 64 < 256) LOAD(kk0 + 64);
    #pragma unroll
    for (int ks = 0; ks < 2; ++ks) {
      bfx8 af = *(const bfx8*)&at[w * 16 + ln15][ks * 32 + g * 8];
      #pragma unroll
      for (int nt = 0; nt < 8; ++nt) {
        bfx8 bf = *(const bfx8*)&bt[nt * 16 + ln15][ks * 32 + g * 8];
        acc[nt] = __builtin_amdgcn_mfma_f32_16x16x32_bf16(af, bf, acc[nt], 0, 0, 0);
      }
    }
  }

  #pragma unroll
  for (int nt = 0; nt < 8; ++nt) {
    int col = n0 + nt * 16 + ln15;
    float bb = bias[col];
    #pragma unroll
    for (int r = 0; r < 4; ++r) {
      int row = m0 + w * 16 + g * 4 + r;
      float val = acc[nt][r] + bb;
      if (OUT_BF16) ((short*)C)[(size_t)row * ldc + col] = f2bf(val);
      else          ((float*)C)[(size_t)row * ldc + col] = val;
    }
  }
}

// ---------------- fused merge+proj for layer 0 (nchunk=2) --------------------
// A-tile staging merges the two flash-decode partials on the fly:
// A[s][head hh2, dim d] = (pO0*w0 + pO1*w1)/L  with per-(s,hh2) M/L scalars.
// Removes k_amerge + the 4MB ctx round-trip. MFMA body = k_gemm's.
__global__ __launch_bounds__(256) void k_pmerge(const short* __restrict__ partO,
                                                const float* __restrict__ partML,
                                                const short* __restrict__ BT,
                                                const float* __restrict__ bias,
                                                float* __restrict__ C) {
  constexpr int LP = 76;
  __shared__ short at[64][LP];
  __shared__ short bt[128][LP];
  int tid = threadIdx.x;
  int w = tid >> 6, lane = tid & 63, ln15 = lane & 15, g = lane >> 4;
  int m0 = blockIdx.x * 64;
  int n0 = blockIdx.y * 128;
  int srow = tid >> 2, scol = (tid & 3) * 16;
  int brow = tid >> 1, bcol = (tid & 1) * 32;

  int grow = m0 + srow;
  int b = grow >> 11, s = grow & 2047;     // NS = 2048

  f32x4 acc[8];
  #pragma unroll
  for (int nt = 0; nt < 8; ++nt) acc[nt] = (f32x4){0.f, 0.f, 0.f, 0.f};

  bfx8 a0, a1, b0_, b1_, b2_, b3_;
  auto LOAD = [&](int kk0) {
    // ---- A: merged partials for head hh2 = kk0>>6, dims scol..scol+15 ----
    int hh2 = kk0 >> 6;
    size_t r0 = (size_t)(b * NH + hh2) * NS + s;       // chunk 0
    size_t r1 = r0 + (size_t)16 * NS;                  // chunk 1
    float2 ml0 = *(const float2*)&partML[r0 * 2];
    float2 ml1 = *(const float2*)&partML[r1 * 2];
    float M = fmaxf(ml0.x, ml1.x);
    float wA = exp2_hw(ml0.x - M), wB = exp2_hw(ml1.x - M);
    float inv = 1.f / (ml0.y * wA + ml1.y * wB);
    wA *= inv; wB *= inv;
    union { int4 v; short sh[8]; } c0a, c0b, c1a, c1b;
    c0a.v = *(const int4*)&partO[r0 * 64 + scol];
    c0b.v = *(const int4*)&partO[r0 * 64 + scol + 8];
    c1a.v = *(const int4*)&partO[r1 * 64 + scol];
    c1b.v = *(const int4*)&partO[r1 * 64 + scol + 8];
    union { bfx8 v; short sh[8]; } ua, ub;
    #pragma unroll
    for (int i = 0; i < 8; ++i) {
      ua.sh[i] = f2bf(bf2f(c0a.sh[i]) * wA + bf2f(c1a.sh[i]) * wB);
      ub.sh[i] = f2bf(bf2f(c0b.sh[i]) * wA + bf2f(c1b.sh[i]) * wB);
    }
    a0 = ua.v; a1 = ub.v;
    // ---- B: woT rows ----
    const short* bs = &BT[(size_t)(n0 + brow) * 256 + kk0 + bcol];
    b0_ = *(const bfx8*)bs; b1_ = *(const bfx8*)(bs + 8);
    b2_ = *(const bfx8*)(bs + 16); b3_ = *(const bfx8*)(bs + 24);
  };
  LOAD(0);
  for (int kk0 = 0; kk0 < 256; kk0 += 64) {
    __syncthreads();
    *(bfx8*)&at[srow][scol] = a0; *(bfx8*)&at[srow][scol + 8] = a1;
    *(bfx8*)&bt[brow][bcol] = b0_; *(bfx8*)&bt[brow][bcol + 8] = b1_;
    *(bfx8*)&bt[brow][bcol + 16] = b2_; *(bfx8*)&bt[brow][bcol + 24] = b3_;
    __syncthreads();
    if (kk0 + 64 < 256) LOAD(kk0 + 64);
    #pragma unroll
    for (int ks = 0; ks < 2; ++ks) {
      bfx8 af = *(const bfx8*)&at[w * 16 + ln15][ks * 32 + g * 8];
      #pragma unroll
      for (int nt = 0; nt < 8; ++nt) {
        bfx8 bf = *(const bfx8*)&bt[nt * 16 + ln15][ks * 32 + g * 8];
        acc[nt] = __builtin_amdgcn_mfma_f32_16x16x32_bf16(af, bf, acc[nt], 0, 0, 0);
      }
    }
  }

  #pragma unroll
  for (int nt = 0; nt < 8; ++nt) {
    int col = n0 + nt * 16 + ln15;
    float bb = bias[col];
    #pragma unroll
    for (int r = 0; r < 4; ++r) {
      int row = m0 + w * 16 + g * 4 + r;
      C[(size_t)row * 256 + col] = acc[nt][r] + bb;
    }
  }
}

// ---------------- V^T + bias prepass (per layer) -----------------------------
__global__ __launch_bounds__(256) void k_frag(const short* __restrict__ qkv,
                                              const int* __restrict__ td,
                                              const int* __restrict__ mask,
                                              const float* __restrict__ tp,
                                              short* __restrict__ vT,
                                              float* __restrict__ sbias_g) {
  __shared__ short vl[64][72];
  int tile = blockIdx.x, hh = blockIdx.y, b = blockIdx.z;
  int t = threadIdx.x;
  int k0 = tile * 64;
  {
    int key = t >> 2, dg = (t & 3) * 16;
    const short* vsrc = &qkv[(size_t)(b * NS + k0 + key) * 768 + 512 + hh * NDK + dg];
    bfx8 v0 = *(const bfx8*)vsrc, v1 = *(const bfx8*)(vsrc + 8);
    *(bfx8*)&vl[key][dg] = v0;
    *(bfx8*)&vl[key][dg + 8] = v1;
  }
  if (t < 64) {
    int kk = k0 + t;
    int tb = td[b * NS + kk];
    tb = tb < 0 ? 0 : (tb >= NT ? NT - 1 : tb);
    sbias_g[(size_t)(b * NH + hh) * NS + kk] = mask[b * NS + kk] ? tp[tb * NH + hh] * L2E : -1e9f;
  }
  __syncthreads();
  int dim = t >> 2, c0 = (t & 3) * 16;
  short outv[16];
  #pragma unroll
  for (int j = 0; j < 16; ++j) {
    int c = c0 + j;
    int kk = ((c >> 5) << 5) | (((c >> 2) & 1) << 4) | (((c >> 3) & 3) << 2) | (c & 3);
    outv[j] = vl[kk][dim];
  }
  short* dst = &vT[(((size_t)(b * NH + hh) * 32 + tile) * 64 + dim) * 64 + c0];
  *(int4*)dst = *(const int4*)outv;
  *(int4*)(dst + 8) = *(const int4*)(outv + 8);
}

// ---------------- MFMA flash attention (R12 version, proven 41.5us) ----------
__global__ __launch_bounds__(512, 4) void k_attn(const short* __restrict__ qkv,
                                                 const short* __restrict__ vT,
                                                 const float* __restrict__ sbias_g,
                                                 short* __restrict__ ctx,
                                                 short* __restrict__ partO,
                                                 float* __restrict__ partML,
                                                 int q_base, int qcount, int nchunk) {
  constexpr int LPK = 76;
  constexpr int LPV = 76;
  __shared__ short kt[2][64][LPK];
  __shared__ short vt[2][64][LPV];
  __shared__ float sbias[2][64];
  __shared__ float shML[128];

  int tid = threadIdx.x;
  int w = tid >> 6, lane = tid & 63, ln15 = lane & 15, g = lane >> 4;
  int half = w >> 2, wsub = w & 3;
  int t = tid & 255;
  int b = blockIdx.z, hh = blockIdx.y;
  int qtile = blockIdx.x / nchunk;
  int chunk = blockIdx.x - qtile * nchunk;
  int niter = NS / (128 * nchunk);
  int tbase = chunk * (NS / 64 / nchunk);
  int q0 = q_base + qtile * 64;
  int qw0 = q0 + wsub * 16;

  bfx8 aq[2];
  #pragma unroll
  for (int ks = 0; ks < 2; ++ks)
    aq[ks] = *(const bfx8*)&qkv[(size_t)(b * NS + qw0 + ln15) * 768 + hh * NDK + ks * 32 + g * 8];

  f32x4 o[4];
  #pragma unroll
  for (int dt = 0; dt < 4; ++dt) o[dt] = (f32x4){0.f, 0.f, 0.f, 0.f};
  float m = -1e30f, lsum = 0.f;

  int srow = t >> 2, scg = (t & 3) * 16;

  bfx8 kr0, kr1, vr0, vr1;
  float br = 0.f;
  auto loadset = [&](int it) {
    int tt = tbase + half * niter + it;
    int k0 = tt * 64;
    const short* ksrc = &qkv[(size_t)(b * NS + k0 + srow) * 768 + 256 + hh * NDK + scg];
    kr0 = *(const bfx8*)ksrc; kr1 = *(const bfx8*)(ksrc + 8);
    const short* vsrc = &vT[(((size_t)(b * NH + hh) * 32 + tt) * 64 + srow) * 64 + scg];
    vr0 = *(const bfx8*)vsrc; vr1 = *(const bfx8*)(vsrc + 8);
    if (t < 64) br = sbias_g[(size_t)(b * NH + hh) * NS + k0 + t];
  };

  auto compute = [&]() {
    f32x4 c[4];
    __builtin_amdgcn_s_setprio(1);
    #pragma unroll
    for (int nt = 0; nt < 4; ++nt) {
      c[nt] = (f32x4){0.f, 0.f, 0.f, 0.f};
      #pragma unroll
      for (int ks = 0; ks < 2; ++ks) {
        bfx8 kf = *(const bfx8*)&kt[half][nt * 16 + ln15][ks * 32 + g * 8];
        c[nt] = __builtin_amdgcn_mfma_f32_16x16x32_bf16(kf, aq[ks], c[nt], 0, 0, 0);
      }
    }
    __builtin_amdgcn_s_setprio(0);
    #pragma unroll
    for (int nt = 0; nt < 4; ++nt) {
      float4 bb = *(const float4*)&sbias[half][nt * 16 + g * 4];
      c[nt][0] += bb.x; c[nt][1] += bb.y; c[nt][2] += bb.z; c[nt][3] += bb.w;
    }
    float rm = c[0][0];
    #pragma unroll
    for (int nt = 0; nt < 4; ++nt)
      #pragma unroll
      for (int r = 0; r < 4; ++r) rm = fmaxf(rm, c[nt][r]);
    rm = fmaxf(rm, __shfl_xor(rm, 16, 64));
    rm = fmaxf(rm, __shfl_xor(rm, 32, 64));
    if (__any(rm > m + 10.f)) {
      float nm = fmaxf(m, rm);
      float scl = exp2_hw(m - nm);
      m = nm;
      lsum *= scl;
      #pragma unroll
      for (int dt = 0; dt < 4; ++dt)
        #pragma unroll
        for (int r = 0; r < 4; ++r) o[dt][r] *= scl;
    }
    unsigned pb[2][4];
    float ts = 0.f;
    #pragma unroll
    for (int nt = 0; nt < 4; ++nt) {
      float e0 = exp2_hw(c[nt][0] - m), e1 = exp2_hw(c[nt][1] - m);
      float e2 = exp2_hw(c[nt][2] - m), e3 = exp2_hw(c[nt][3] - m);
      ts += (e0 + e1) + (e2 + e3);
      pb[nt >> 1][(nt & 1) * 2]     = cvt_pk_bf16(e0, e1);
      pb[nt >> 1][(nt & 1) * 2 + 1] = cvt_pk_bf16(e2, e3);
    }
    lsum += ts;
    __builtin_amdgcn_s_setprio(1);
    #pragma unroll
    for (int ks = 0; ks < 2; ++ks) {
      union { unsigned u[4]; bfx8 v; } pf;
      pf.u[0] = pb[ks][0]; pf.u[1] = pb[ks][1]; pf.u[2] = pb[ks][2]; pf.u[3] = pb[ks][3];
      #pragma unroll
      for (int dt = 0; dt < 4; ++dt) {
        bfx8 vf = *(const bfx8*)&vt[half][dt * 16 + ln15][ks * 32 + g * 8];
        o[dt] = __builtin_amdgcn_mfma_f32_16x16x32_bf16(vf, pf.v, o[dt], 0, 0, 0);
      }
    }
    __builtin_amdgcn_s_setprio(0);
  };

  loadset(0);
  for (int it = 0; it < niter; ++it) {
    __syncthreads();
    *(bfx8*)&kt[half][srow][scg] = kr0;
    *(bfx8*)&kt[half][srow][scg + 8] = kr1;
    *(bfx8*)&vt[half][srow][scg] = vr0;
    *(bfx8*)&vt[half][srow][scg + 8] = vr1;
    if (t < 64) sbias[half][t] = br;
    __syncthreads();
    if (it + 1 < niter) loadset(it + 1);
    compute();
  }

  lsum += __shfl_xor(lsum, 16, 64);
  lsum += __shfl_xor(lsum, 32, 64);

  float* shO = (float*)&kt[0][0][0];
  __syncthreads();
  int q = wsub * 16 + ln15;
  if (half == 1) {
    #pragma unroll
    for (int dt = 0; dt < 4; ++dt) {
      float4 st; st.x = o[dt][0]; st.y = o[dt][1]; st.z = o[dt][2]; st.w = o[dt][3];
      *(float4*)&shO[q * 68 + dt * 16 + g * 4] = st;
    }
    if (g == 0) { shML[q * 2] = m; shML[q * 2 + 1] = lsum; }
  }
  __syncthreads();
  if (half == 0) {
    float m2 = shML[q * 2], l2 = shML[q * 2 + 1];
    float M = fmaxf(m, m2);
    float fa = exp2_hw(m - M), fb = exp2_hw(m2 - M);
    if (nchunk == 1) {
      float inv = 1.f / (lsum * fa + l2 * fb);
      fa *= inv; fb *= inv;
      #pragma unroll
      for (int dt = 0; dt < 4; ++dt) {
        float4 sh = *(const float4*)&shO[q * 68 + dt * 16 + g * 4];
        float v0 = o[dt][0] * fa + sh.x * fb;
        float v1 = o[dt][1] * fa + sh.y * fb;
        float v2 = o[dt][2] * fa + sh.z * fb;
        float v3 = o[dt][3] * fa + sh.w * fb;
        int2 pk; pk.x = (int)cvt_pk_bf16(v0, v1); pk.y = (int)cvt_pk_bf16(v2, v3);
        *(int2*)&ctx[(size_t)(b * NS + q0 + q) * ND + hh * NDK + dt * 16 + g * 4] = pk;
      }
    } else {
      float L = lsum * fa + l2 * fb;
      size_t rowi = (size_t)(chunk * 16 + b * NH + hh) * qcount + qtile * 64 + q;
      #pragma unroll
      for (int dt = 0; dt < 4; ++dt) {
        float4 sh = *(const float4*)&shO[q * 68 + dt * 16 + g * 4];
        float v0 = o[dt][0] * fa + sh.x * fb;
        float v1 = o[dt][1] * fa + sh.y * fb;
        float v2 = o[dt][2] * fa + sh.z * fb;
        float v3 = o[dt][3] * fa + sh.w * fb;
        int2 pk; pk.x = (int)cvt_pk_bf16(v0, v1); pk.y = (int)cvt_pk_bf16(v2, v3);
        *(int2*)&partO[rowi * 64 + dt * 16 + g * 4] = pk;
      }
      if (g == 0) { partML[rowi * 2] = M; partML[rowi * 2 + 1] = L; }
    }
  }
}

// ---------------- flash-decode merge (layer 1 only) --------------------------
__global__ __launch_bounds__(256) void k_amerge(const short* __restrict__ partO,
                                                const float* __restrict__ partML,
                                                short* __restrict__ ctx,
                                                int q_base, int qcount, int nchunk) {
  int b = blockIdx.z, hh = blockIdx.y;
  int qi = blockIdx.x * 64 + (threadIdx.x >> 2);
  int d0 = (threadIdx.x & 3) * 16;
  int bh = b * NH + hh;
  float M = -1e30f;
  for (int c = 0; c < nchunk; ++c)
    M = fmaxf(M, partML[((size_t)(c * 16 + bh) * qcount + qi) * 2]);
  float L = 0.f;
  float acc[16];
  #pragma unroll
  for (int i = 0; i < 16; ++i) acc[i] = 0.f;
  for (int c = 0; c < nchunk; ++c) {
    size_t row = (size_t)(c * 16 + bh) * qcount + qi;
    float mc = partML[row * 2];
    float lc = partML[row * 2 + 1];
    float s = exp2_hw(mc - M);
    L += lc * s;
    union { int4 v; short sh[8]; } u0, u1;
    u0.v = *(const int4*)&partO[row * 64 + d0];
    u1.v = *(const int4*)&partO[row * 64 + d0 + 8];
    #pragma unroll
    for (int i = 0; i < 8; ++i) {
      acc[i]     += bf2f(u0.sh[i]) * s;
      acc[8 + i] += bf2f(u1.sh[i]) * s;
    }
  }
  float inv = 1.f / L;
  short res[16];
  #pragma unroll
  for (int i = 0; i < 16; ++i) res[i] = f2bf(acc[i] * inv);
  short* dst = &ctx[(size_t)(b * NS + q_base + qi) * ND + hh * NDK + d0];
  *(int4*)dst = *(const int4*)res;
  *(int4*)(dst + 8) = *(const int4*)(res + 8);
}

// ---------------- layernorm: 4 rows/block, shuffle-reduce --------------------
__global__ __launch_bounds__(256) void k_ln(float* __restrict__ h,
                                            short* __restrict__ hb,
                                            const float* __restrict__ g_,
                                            const float* __restrict__ b_, int q_base) {
  int lane = threadIdx.x & 63, r4 = threadIdx.x >> 6;
  size_t row = (size_t)blockIdx.y * NS + q_base + blockIdx.x * 4 + r4;
  float4 v = ((const float4*)&h[row * ND])[lane];
  float s = v.x + v.y + v.z + v.w;
  #pragma unroll
  for (int off = 1; off < 64; off <<= 1) s += __shfl_xor(s, off, 64);
  float mu = s * (1.f / ND);
  float dx = v.x - mu, dy = v.y - mu, dz = v.z - mu, dw = v.w - mu;
  float q = dx * dx + dy * dy + dz * dz + dw * dw;
  #pragma unroll
  for (int off = 1; off < 64; off <<= 1) q += __shfl_xor(q, off, 64);
  float rr = rsqrtf(q * (1.f / ND) + 1e-5f);
  float4 gg = ((const float4*)g_)[lane];
  float4 bb = ((const float4*)b_)[lane];
  float4 o;
  o.x = dx * rr * gg.x + bb.x;
  o.y = dy * rr * gg.y + bb.y;
  o.z = dz * rr * gg.z + bb.z;
  o.w = dw * rr * gg.w + bb.w;
  ((float4*)&h[row * ND])[lane] = o;
  short4 ob; ob.x = f2bf(o.x); ob.y = f2bf(o.y); ob.z = f2bf(o.z); ob.w = f2bf(o.w);
  ((short4*)&hb[row * ND])[lane] = ob;
}

// ---------------- classifier head on last token ------------------------------
__global__ __launch_bounds__(128) void k_head(const float* __restrict__ h,
                                              const float* __restrict__ Wc1,
                                              const float* __restrict__ bc1,
                                              const float* __restrict__ Wc2,
                                              const float* __restrict__ bc2,
                                              float* __restrict__ out) {
  __shared__ float red[128];
  int j = threadIdx.x;
  int b = blockIdx.x;
  const float* last = &h[(size_t)(b * NS + NS - 1) * ND];
  float acc = bc1[j];
  for (int d = 0; d < ND; ++d) acc = fmaf(last[d], Wc1[d * 128 + j], acc);
  acc = fmaxf(acc, 0.f);
  red[j] = acc * Wc2[j];
  __syncthreads();
  for (int off = 64; off > 0; off >>= 1) {
    if (j < off) red[j] += red[j + off];
    __syncthreads();
  }
  if (j == 0) out[b] = 1.f / (1.f + __expf(-(red[0] + bc2[0])));
}

}  // namespace

extern "C" void kernel_launch(void* const* d_in, const int* in_sizes, int n_in,
                              void* d_out, int out_size, void* d_ws, size_t ws_size,
                              hipStream_t stream) {
  const int* x = (const int*)d_in[0];
  const int* td = (const int*)d_in[1];
  const int* mask = (const int*)d_in[2];
  const float* ee = (const float*)d_in[3];
  const float* te = (const float*)d_in[4];
  const float* Wq = (const float*)d_in[5];
  const float* bq = (const float*)d_in[6];
  const float* Wk = (const float*)d_in[7];
  const float* bk = (const float*)d_in[8];
  const float* Wv = (const float*)d_in[9];
  const float* bv = (const float*)d_in[10];
  const float* tp = (const float*)d_in[11];
  const float* Wo = (const float*)d_in[12];
  const float* bo = (const float*)d_in[13];
  const float* lng = (const float*)d_in[14];
  const float* lnb = (const float*)d_in[15];
  const float* Wc1 = (const float*)d_in[16];
  const float* bc1 = (const float*)d_in[17];
  const float* Wc2 = (const float*)d_in[18];
  const float* bc2 = (const float*)d_in[19];
  float* out = (float*)d_out;

  char* ws = (char*)d_ws;
  const size_t M = (size_t)NB * NS;  // 8192
  // Flat layout, no overlays for layer-0 (fused merge-proj reads partO while
  // writing h). Total footprint ~38.4 MB.
  short* qkv     = (short*)(ws);                          // 12 MB [M][768]
  float* h       = (float*)(ws + (12 << 20));             // 8 MB
  short* hb      = (short*)(ws + (20 << 20));             // 4 MB
  short* vT      = (short*)(ws + (24 << 20));             // 4 MB (l1: ctx overlays after attn)
  float* sbias_g = (float*)(ws + (28 << 20));             // 128 KB
  short* wqkvT   = (short*)(ws + (28 << 20) + (128 << 10)); // 768 KB
  short* woT     = (short*)(ws + (28 << 20) + (896 << 10)); // 256 KB
  float* bqkv    = (float*)(ws + (28 << 20) + (1152 << 10)); // 8 KB
  float* partML  = (float*)(ws + (29 << 20) + (512 << 10)); // 512 KB
  short* partO   = (short*)(ws + (30 << 20));             // 8.4 MB
  short* ctx1    = vT;   // layer-1 ctx reuses vT region (dead after attn l1)

  k_packw<<<dim3(4, 4, 8), 256, 0, stream>>>(Wq, Wk, Wv, Wo, bq, bk, bv, wqkvT, woT, bqkv);
  k_embed<<<NB * NS / 4, 256, 0, stream>>>(x, td, ee, te, h, hb);

  for (int l = 0; l < NL; ++l) {
    const short* wqkvTl = wqkvT + (size_t)l * 768 * 256;
    const short* woTl = woT + (size_t)l * 65536;
    const float* bqkvl = bqkv + (size_t)l * 768;
    const float* bol = bo + (size_t)l * ND;
    const float* tpl = tp + (size_t)l * NT * NH;
    const float* lngl = lng + (size_t)l * ND;
    const float* lnbl = lnb + (size_t)l * ND;
    const bool last = (l == NL - 1);

    if (!last) {
      k_gemm<1><<<dim3(M / 64, 6), 256, 0, stream>>>(hb, wqkvTl, bqkvl, qkv, 768, 1, 0, 0);
    } else {
      k_gemm<1><<<dim3(M / 64, 4), 256, 0, stream>>>(hb, wqkvTl, bqkvl, qkv, 768, 1, 0, 256);
      k_gemm<1><<<dim3(NB, 2), 256, 0, stream>>>(hb, wqkvTl, bqkvl, qkv, 768, 32, 31, 0);
    }

    k_frag<<<dim3(32, NH, NB), 256, 0, stream>>>(qkv, td, mask, tpl, vT, sbias_g);

    if (!last) {
      k_attn<<<dim3((NS / 64) * 2, NH, NB), 512, 0, stream>>>(qkv, vT, sbias_g, partO,
                                                              partO, partML, 0, NS, 2);
      k_pmerge<<<dim3(M / 64, 2), 256, 0, stream>>>(partO, partML, woTl, bol, h);
      k_ln<<<dim3(NS / 4, NB), 256, 0, stream>>>(h, hb, lngl, lnbl, 0);
    } else {
      k_attn<<<dim3(16, NH, NB), 512, 0, stream>>>(qkv, vT, sbias_g, ctx1,
                                                   partO, partML, NS - 64, 64, 16);
      k_amerge<<<dim3(1, NH, NB), 256, 0, stream>>>(partO, partML, ctx1, NS - 64, 64, 16);
      k_gemm<0><<<dim3(NB, 2), 256, 0, stream>>>(ctx1, woTl, bol, h, 256, 32, 31, 0);
      k_ln<<<dim3(1, NB), 256, 0, stream>>>(h, hb, lngl, lnbl, NS - 4);
    }
  }

  k_head<<<NB, 128, 0, stream>>>(h, Wc1, bc1, Wc2, bc2, out);
}